// Round 1
// 738.563 us; speedup vs baseline: 1.0199x; 1.0199x over previous
//
#include <hip/hip_runtime.h>
#include <math.h>

#define NPIX 9216   // 96*96
#define BATCH 8
#define HEADS 8

typedef __bf16 bf16;
typedef __bf16 bf16x8 __attribute__((ext_vector_type(8)));
typedef __bf16 bf16x4 __attribute__((ext_vector_type(4)));
typedef __bf16 bf16x2 __attribute__((ext_vector_type(2)));
typedef float f32x4 __attribute__((ext_vector_type(4)));

__device__ __forceinline__ void load_lds16(const bf16* g, bf16* l) {
  __builtin_amdgcn_global_load_lds(
      (const __attribute__((address_space(1))) void*)g,
      (__attribute__((address_space(3))) void*)l, 16, 0, 0);
}

// ---------- fp32 -> bf16 elementwise ----------
__global__ __launch_bounds__(256) void cvt_f2b(const float* __restrict__ in,
                                               bf16* __restrict__ out, int n) {
  int i = blockIdx.x * 256 + threadIdx.x;
  if (i < n) out[i] = (bf16)in[i];
}

// ---------- transpose+cvt: (B,C,N) fp32 -> (B,N,C) bf16  AND (B,C,N) bf16 ----------
__global__ __launch_bounds__(256) void transpose_cvt(
    const float* __restrict__ in, bf16* __restrict__ out,
    bf16* __restrict__ outN, int C, int N) {
  __shared__ float tile[32][33];
  int b = blockIdx.z;
  int n0 = blockIdx.x * 32, c0 = blockIdx.y * 32;
  int tx = threadIdx.x & 31, ty = threadIdx.x >> 5;
#pragma unroll
  for (int k = 0; k < 4; ++k) {
    float v = in[((size_t)b * C + c0 + ty + k * 8) * N + n0 + tx];
    tile[ty + k * 8][tx] = v;
    outN[((size_t)b * C + c0 + ty + k * 8) * N + n0 + tx] = (bf16)v;
  }
  __syncthreads();
#pragma unroll
  for (int k = 0; k < 4; ++k)
    out[((size_t)b * N + n0 + ty + k * 8) * C + c0 + tx] = (bf16)tile[tx][ty + k * 8];
}

// ---------- fused channel-softmax (512 ch) + rowsum + optional transpose ----------
__global__ __launch_bounds__(256) void softmax_fused(
    bf16* __restrict__ A, float* __restrict__ S, bf16* __restrict__ At,
    int N, int writeT) {
  __shared__ bf16 tile[512][34];
  __shared__ float redm[8][32];
  __shared__ float reds[8][32];
  int b = blockIdx.y;
  int n0 = blockIdx.x * 32;
  bf16* Ab = A + (size_t)b * 512 * N;
  int t = threadIdx.x;
#pragma unroll 8
  for (int i = 0; i < 32; ++i) {
    int idx = i * 256 + t;
    int c = idx >> 4, ch = idx & 15;
    *(bf16x2*)&tile[c][ch * 2] = *(const bf16x2*)&Ab[(size_t)c * N + n0 + ch * 2];
  }
  __syncthreads();
  int n = t & 31, oct = t >> 5;
  float m = -1e30f;
#pragma unroll 8
  for (int k = 0; k < 64; ++k) m = fmaxf(m, (float)tile[k * 8 + oct][n]);
  redm[oct][n] = m;
  __syncthreads();
  if (t < 32) {
    float mm = redm[0][t];
#pragma unroll
    for (int o = 1; o < 8; ++o) mm = fmaxf(mm, redm[o][t]);
    redm[0][t] = mm;
  }
  __syncthreads();
  float mm = redm[0][n];
  float s = 0.f;
#pragma unroll 8
  for (int k = 0; k < 64; ++k) {
    int c = k * 8 + oct;
    float e = expf((float)tile[c][n] - mm);
    s += e;
    tile[c][n] = (bf16)e;
  }
  reds[oct][n] = s;
  __syncthreads();
  if (t < 32) {
    float ss = reds[0][t];
#pragma unroll
    for (int o = 1; o < 8; ++o) ss += reds[o][t];
    reds[0][t] = ss;
  }
  __syncthreads();
  float inv = 1.f / reds[0][n];
#pragma unroll 8
  for (int k = 0; k < 64; ++k) {
    int c = k * 8 + oct;
    tile[c][n] = (bf16)((float)tile[c][n] * inv);
  }
  __syncthreads();
#pragma unroll 8
  for (int i = 0; i < 32; ++i) {
    int idx = i * 256 + t;
    int c = idx >> 4, ch = idx & 15;
    *(bf16x2*)&Ab[(size_t)c * N + n0 + ch * 2] = *(const bf16x2*)&tile[c][ch * 2];
  }
  {
    int c0 = 2 * t, c1 = 2 * t + 1;
    float s0 = 0.f, s1 = 0.f;
#pragma unroll 8
    for (int nn = 0; nn < 32; ++nn) {
      s0 += (float)tile[c0][nn];
      s1 += (float)tile[c1][nn];
    }
    atomicAdd(&S[(size_t)b * 512 + c0], s0);
    atomicAdd(&S[(size_t)b * 512 + c1], s1);
  }
  if (writeT) {
    bf16* Atb = At + (size_t)b * N * 512;
#pragma unroll 4
    for (int nn = 0; nn < 32; ++nn) {
      bf16x2 v = {tile[2 * t][nn], tile[2 * t + 1][nn]};
      *(bf16x2*)&Atb[(size_t)(n0 + nn) * 512 + 2 * t] = v;
    }
  }
}

// ---------- MFMA conv: Y[b,o,n](bf16) = bias[o] + sum_c W[o,c]*Xt[b,n,c] ----------
__global__ __launch_bounds__(256) void mfma_conv(
    const bf16* __restrict__ W, const float* __restrict__ bias,
    const bf16* __restrict__ Xt, bf16* __restrict__ Y, int O, int N) {
  const int K = 256;
  __shared__ bf16 As[128 * 32];
  __shared__ bf16 Bs[128 * 32];
  int b = blockIdx.z;
  int n0 = blockIdx.x * 128, o0 = blockIdx.y * 128;
  const bf16* Xb = Xt + (size_t)b * N * K;
  int t = threadIdx.x;
  int lane = t & 63, wave = t >> 6;
  int wr = wave >> 1, wc = wave & 1;
  f32x4 acc[4][4] = {};
  for (int k0 = 0; k0 < K; k0 += 32) {
#pragma unroll
    for (int p = 0; p < 2; ++p) {
      int u = p * 256 + t;
      int ub = p * 256 + (t & 192);
      load_lds16(&W[(size_t)(o0 + (u >> 2)) * K + k0 + (u & 3) * 8], &As[ub * 8]);
      load_lds16(&Xb[(size_t)(n0 + (u >> 2)) * K + k0 + (u & 3) * 8], &Bs[ub * 8]);
    }
    __syncthreads();
    bf16x8 bfrag[4];
#pragma unroll
    for (int j = 0; j < 4; ++j)
      bfrag[j] = *(const bf16x8*)&Bs[(wc * 64 + j * 16 + (lane & 15)) * 32 + (lane >> 4) * 8];
#pragma unroll
    for (int i = 0; i < 4; ++i) {
      bf16x8 a = *(const bf16x8*)&As[(wr * 64 + i * 16 + (lane & 15)) * 32 + (lane >> 4) * 8];
#pragma unroll
      for (int j = 0; j < 4; ++j)
        acc[i][j] = __builtin_amdgcn_mfma_f32_16x16x32_bf16(a, bfrag[j], acc[i][j], 0, 0, 0);
    }
    __syncthreads();
  }
  bf16* Yb = Y + (size_t)b * O * N;
  int quad = lane >> 4, col16 = lane & 15;
#pragma unroll
  for (int i = 0; i < 4; ++i) {
#pragma unroll
    for (int reg = 0; reg < 4; ++reg) {
      int row = o0 + wr * 64 + i * 16 + quad * 4 + reg;
      float bv = bias[row];
#pragma unroll
      for (int j = 0; j < 4; ++j) {
        int col = n0 + wc * 64 + j * 16 + col16;
        Yb[(size_t)row * N + col] = (bf16)(acc[i][j][reg] + bv);
      }
    }
  }
}

// ---------- gemm_T (MFMA, split-K): Tt[b,r,c] += sum_n Rm[b,r,n]*Xb[b,c,n] ----------
// Both operands bf16, n-contiguous -> pure global_load_lds staging.
__global__ __launch_bounds__(256) void gemm_T_mfma(
    const bf16* __restrict__ Rm, const bf16* __restrict__ Xb_,
    float* __restrict__ Tt, int N) {
  __shared__ bf16 As[128 * 32];
  __shared__ bf16 Bs[128 * 32];
  int z = blockIdx.z;
  int b = z >> 4, ks = z & 15;
  int klen = N / 16;
  int kbase = ks * klen;
  int c0 = blockIdx.x * 128, r0 = blockIdx.y * 128;
  const bf16* Rb = Rm + (size_t)b * 512 * N;
  const bf16* Xc = Xb_ + (size_t)b * 256 * N;
  int t = threadIdx.x;
  int lane = t & 63, wave = t >> 6;
  int wr = wave >> 1, wc = wave & 1;
  f32x4 acc[4][4] = {};
  for (int kk = kbase; kk < kbase + klen; kk += 32) {
#pragma unroll
    for (int p = 0; p < 2; ++p) {
      int u = p * 256 + t;
      int ub = p * 256 + (t & 192);
      load_lds16(&Rb[(size_t)(r0 + (u >> 2)) * N + kk + (u & 3) * 8], &As[ub * 8]);
      load_lds16(&Xc[(size_t)(c0 + (u >> 2)) * N + kk + (u & 3) * 8], &Bs[ub * 8]);
    }
    __syncthreads();
    bf16x8 bfrag[4];
#pragma unroll
    for (int j = 0; j < 4; ++j)
      bfrag[j] = *(const bf16x8*)&Bs[(wc * 64 + j * 16 + (lane & 15)) * 32 + (lane >> 4) * 8];
#pragma unroll
    for (int i = 0; i < 4; ++i) {
      bf16x8 a = *(const bf16x8*)&As[(wr * 64 + i * 16 + (lane & 15)) * 32 + (lane >> 4) * 8];
#pragma unroll
      for (int j = 0; j < 4; ++j)
        acc[i][j] = __builtin_amdgcn_mfma_f32_16x16x32_bf16(a, bfrag[j], acc[i][j], 0, 0, 0);
    }
    __syncthreads();
  }
  int quad = lane >> 4, col16 = lane & 15;
  float* Tb = Tt + (size_t)b * 512 * 256;
#pragma unroll
  for (int i = 0; i < 4; ++i) {
#pragma unroll
    for (int reg = 0; reg < 4; ++reg) {
      int r = r0 + wr * 64 + i * 16 + quad * 4 + reg;
#pragma unroll
      for (int j = 0; j < 4; ++j) {
        int c = c0 + wc * 64 + j * 16 + col16;
        atomicAdd(&Tb[(size_t)r * 256 + c], acc[i][j][reg]);
      }
    }
  }
}

// ---------- fold projections into region space (fp32, LDS-staged, c-split) ----------
// grid (HEADS, BATCH, 4). qr/kr/vr pre-zeroed; atomicAdd accumulate.
__global__ __launch_bounds__(256) void fold_qkv(
    const float* __restrict__ Tt1, const float* __restrict__ Tt2,
    const float* __restrict__ S1, const float* __restrict__ S2,
    const float* __restrict__ Wq, const float* __restrict__ bq,
    const float* __restrict__ Wkv, const float* __restrict__ bkv,
    float* __restrict__ qr, float* __restrict__ kr, float* __restrict__ vr) {
  __shared__ float T1s[64][65];
  __shared__ float T2s[64][65];
  __shared__ float Wqs[32][65];
  __shared__ float Wks[64][65];
  int h = blockIdx.x, b = blockIdx.y;
  int c0 = blockIdx.z * 64;
  int t = threadIdx.x;
  for (int i = t; i < 64 * 64; i += 256) {
    int row = i >> 6, col = i & 63;
    T1s[row][col] = Tt1[((size_t)b * 512 + h * 64 + row) * 256 + c0 + col];
    T2s[row][col] = Tt2[((size_t)b * 512 + h * 64 + row) * 256 + c0 + col];
    Wks[row][col] = Wkv[(size_t)(h * 64 + row) * 256 + c0 + col];
  }
  for (int i = t; i < 32 * 64; i += 256) {
    int row = i >> 6, col = i & 63;
    Wqs[row][col] = Wq[(size_t)(h * 32 + row) * 256 + c0 + col];
  }
  __syncthreads();
  int r = t & 63, d0 = (t >> 6) * 8;
  float aq[8] = {}, ak[8] = {}, av[8] = {};
#pragma unroll 8
  for (int c = 0; c < 64; ++c) {
    float t1 = T1s[r][c];
    float t2 = T2s[r][c];
#pragma unroll
    for (int i = 0; i < 8; ++i) {
      int d = d0 + i;
      aq[i] += Wqs[d][c] * t1;
      ak[i] += Wks[d][c] * t2;
      av[i] += Wks[32 + d][c] * t2;
    }
  }
  if (blockIdx.z == 0) {
    float s1 = S1[(size_t)b * 512 + h * 64 + r];
    float s2 = S2[(size_t)b * 512 + h * 64 + r];
#pragma unroll
    for (int i = 0; i < 8; ++i) {
      int d = d0 + i;
      aq[i] += bq[h * 32 + d] * s1;
      ak[i] += bkv[h * 64 + d] * s2;
      av[i] += bkv[h * 64 + 32 + d] * s2;
    }
  }
  size_t off = ((size_t)b * HEADS + h) * 32 * 64;
#pragma unroll
  for (int i = 0; i < 8; ++i) {
    int d = d0 + i;
    atomicAdd(&qr[off + (size_t)d * 64 + r], aq[i]);
    atomicAdd(&kr[off + (size_t)d * 64 + r], ak[i]);
    atomicAdd(&vr[off + (size_t)d * 64 + r], av[i]);
  }
}

// ---------- region attention + Wout fold (fp32). One block per (b,h). ----------
__global__ __launch_bounds__(256) void region_attn(
    const float* __restrict__ qr, const float* __restrict__ kr,
    const float* __restrict__ vr, const float* __restrict__ Wout,
    float* __restrict__ M) {
  int h = blockIdx.x, b = blockIdx.y;
  __shared__ float qrs[32 * 64];
  __shared__ float krs[32 * 64];
  __shared__ float vrs[32 * 64];
  __shared__ float sc[64][65];
  __shared__ float vals[32][64];
  size_t off = ((size_t)b * HEADS + h) * 32 * 64;
  int t = threadIdx.x;
  for (int i = t; i < 2048; i += 256) {
    qrs[i] = qr[off + i];
    krs[i] = kr[off + i];
    vrs[i] = vr[off + i];
  }
  __syncthreads();
  for (int idx = t; idx < 4096; idx += 256) {
    int qq = idx >> 6, kk = idx & 63;
    float s = 0.f;
#pragma unroll
    for (int d = 0; d < 32; ++d) s += qrs[d * 64 + qq] * krs[d * 64 + kk];
    sc[qq][kk] = s * 0.17677669529663687f;
  }
  __syncthreads();
  if (t < 64) {
    float m = -1e30f;
    for (int k = 0; k < 64; ++k) m = fmaxf(m, sc[t][k]);
    float s = 0.f;
    for (int k = 0; k < 64; ++k) { float e = expf(sc[t][k] - m); sc[t][k] = e; s += e; }
    float inv = 1.f / s;
    for (int k = 0; k < 64; ++k) sc[t][k] *= inv;
  }
  __syncthreads();
  for (int idx = t; idx < 2048; idx += 256) {
    int d = idx >> 6, qq = idx & 63;
    float s = 0.f;
#pragma unroll
    for (int k = 0; k < 64; ++k) s += vrs[d * 64 + k] * sc[qq][k];
    vals[d][qq] = s;
  }
  __syncthreads();
  int o = t;
  float w[32];
#pragma unroll
  for (int d = 0; d < 32; ++d) w[d] = Wout[(size_t)o * 256 + h * 32 + d];
  float* Mp = M + ((size_t)b * 256 + o) * 512 + h * 64;
  for (int r = 0; r < 64; ++r) {
    float s = 0.f;
#pragma unroll
    for (int d = 0; d < 32; ++d) s += w[d] * vals[d][r];
    Mp[r] = s;
  }
}

// ---------- final MFMA: out[b,o,n] = tgt + alpha*(bout[o] + sum_j M[b,o,j]*Rqt[b,n,j]) ----------
__global__ __launch_bounds__(256) void mfma_final(
    const bf16* __restrict__ Mb_, const float* __restrict__ bout,
    const bf16* __restrict__ Rqt, const float* __restrict__ tgt,
    const float* __restrict__ alpha_p, float* __restrict__ Y, int N) {
  const int K = 512;
  __shared__ bf16 As[128 * 32];
  __shared__ bf16 Bs[128 * 32];
  int b = blockIdx.z;
  int n0 = blockIdx.x * 128, o0 = blockIdx.y * 128;
  const bf16* Ab = Mb_ + (size_t)b * 256 * K;
  const bf16* Bb = Rqt + (size_t)b * N * K;
  int t = threadIdx.x;
  int lane = t & 63, wave = t >> 6;
  int wr = wave >> 1, wc = wave & 1;
  f32x4 acc[4][4] = {};
  for (int k0 = 0; k0 < K; k0 += 32) {
#pragma unroll
    for (int p = 0; p < 2; ++p) {
      int u = p * 256 + t;
      int ub = p * 256 + (t & 192);
      load_lds16(&Ab[(size_t)(o0 + (u >> 2)) * K + k0 + (u & 3) * 8], &As[ub * 8]);
      load_lds16(&Bb[(size_t)(n0 + (u >> 2)) * K + k0 + (u & 3) * 8], &Bs[ub * 8]);
    }
    __syncthreads();
    bf16x8 bfrag[4];
#pragma unroll
    for (int j = 0; j < 4; ++j)
      bfrag[j] = *(const bf16x8*)&Bs[(wc * 64 + j * 16 + (lane & 15)) * 32 + (lane >> 4) * 8];
#pragma unroll
    for (int i = 0; i < 4; ++i) {
      bf16x8 a = *(const bf16x8*)&As[(wr * 64 + i * 16 + (lane & 15)) * 32 + (lane >> 4) * 8];
#pragma unroll
      for (int j = 0; j < 4; ++j)
        acc[i][j] = __builtin_amdgcn_mfma_f32_16x16x32_bf16(a, bfrag[j], acc[i][j], 0, 0, 0);
    }
    __syncthreads();
  }
  float alpha = alpha_p[0];
  const float* Tb = tgt + (size_t)b * 256 * N;
  float* Yb = Y + (size_t)b * 256 * N;
  int quad = lane >> 4, col16 = lane & 15;
#pragma unroll
  for (int i = 0; i < 4; ++i) {
#pragma unroll
    for (int reg = 0; reg < 4; ++reg) {
      int row = o0 + wr * 64 + i * 16 + quad * 4 + reg;
      float bv = bout[row];
#pragma unroll
      for (int j = 0; j < 4; ++j) {
        int col = n0 + wc * 64 + j * 16 + col16;
        size_t idx = (size_t)row * N + col;
        Yb[idx] = Tb[idx] + alpha * (acc[i][j][reg] + bv);
      }
    }
  }
}

extern "C" void kernel_launch(void* const* d_in, const int* in_sizes, int n_in,
                              void* d_out, int out_size, void* d_ws, size_t ws_size,
                              hipStream_t stream) {
  const float* src  = (const float*)d_in[0];
  const float* tgt  = (const float*)d_in[1];
  const float* Wq   = (const float*)d_in[2];
  const float* bq   = (const float*)d_in[3];
  const float* Wkv  = (const float*)d_in[4];
  const float* bkv  = (const float*)d_in[5];
  const float* Wrq  = (const float*)d_in[6];
  const float* brq  = (const float*)d_in[7];
  const float* Wrk  = (const float*)d_in[8];
  const float* brk  = (const float*)d_in[9];
  const float* Wout = (const float*)d_in[10];
  const float* bout = (const float*)d_in[11];
  const float* alpha = (const float*)d_in[12];
  float* out = (float*)d_out;

  const int N = NPIX;
  char* p = (char*)d_ws;
  bf16* xt    = (bf16*)p;  p += (size_t)BATCH * N * 256 * 2;        // 37.7 MB
  bf16* buf1  = (bf16*)p;  p += (size_t)BATCH * 512 * N * 2;        // 75.5 MB
  bf16* buf2  = (bf16*)p;  p += (size_t)BATCH * 512 * N * 2;        // 75.5 MB
  float* Tt1  = (float*)p; p += (size_t)BATCH * 512 * 256 * 4;      // 4 MB
  float* Tt2  = (float*)p; p += (size_t)BATCH * 512 * 256 * 4;      // 4 MB
  float* S1   = (float*)p; p += (size_t)BATCH * 512 * 4;
  float* S2   = (float*)p; p += (size_t)BATCH * 512 * 4;
  float* qr   = (float*)p; p += (size_t)BATCH * HEADS * 32 * 64 * 4;
  float* kr   = (float*)p; p += (size_t)BATCH * HEADS * 32 * 64 * 4;
  float* vr   = (float*)p; p += (size_t)BATCH * HEADS * 32 * 64 * 4;
  float* Mf   = (float*)p; p += (size_t)BATCH * 256 * 512 * 4;      // 4 MB
  bf16* Wrk_b = (bf16*)p;  p += (size_t)512 * 256 * 2;
  bf16* Wrq_b = (bf16*)p;  p += (size_t)512 * 256 * 2;
  bf16* M_b   = (bf16*)p;  p += (size_t)BATCH * 256 * 512 * 2;
  bf16* xb    = (bf16*)p;  p += (size_t)BATCH * 256 * N * 2;        // 37.7 MB (shared by both phases)

  dim3 blk(256);
  // zero accumulators: Tt1,Tt2,S1,S2,qr,kr,vr are contiguous in ws
  hipMemsetAsync(Tt1, 0,
                 ((size_t)2 * BATCH * 512 * 256 + (size_t)2 * BATCH * 512 +
                  (size_t)3 * BATCH * HEADS * 32 * 64) * 4,
                 stream);
  // weights -> bf16
  cvt_f2b<<<dim3(512 * 256 / 256), blk, 0, stream>>>(Wrk, Wrk_b, 512 * 256);
  cvt_f2b<<<dim3(512 * 256 / 256), blk, 0, stream>>>(Wrq, Wrq_b, 512 * 256);

  // ---- Rk phase ----
  transpose_cvt<<<dim3(N / 32, 8, BATCH), blk, 0, stream>>>(src, xt, xb, 256, N);
  mfma_conv<<<dim3(N / 128, 4, BATCH), blk, 0, stream>>>(Wrk_b, brk, xt, buf1, 512, N);
  softmax_fused<<<dim3(N / 32, BATCH), blk, 0, stream>>>(buf1, S2, (bf16*)nullptr, N, 0);
  gemm_T_mfma<<<dim3(2, 4, BATCH * 16), blk, 0, stream>>>(buf1, xb, Tt2, N);

  // ---- Rq phase ----
  transpose_cvt<<<dim3(N / 32, 8, BATCH), blk, 0, stream>>>(tgt, xt, xb, 256, N);
  mfma_conv<<<dim3(N / 128, 4, BATCH), blk, 0, stream>>>(Wrq_b, brq, xt, buf2, 512, N);
  softmax_fused<<<dim3(N / 32, BATCH), blk, 0, stream>>>(buf2, S1, buf1, N, 1);
  gemm_T_mfma<<<dim3(2, 4, BATCH * 16), blk, 0, stream>>>(buf2, xb, Tt1, N);

  // ---- fold, attention, back-projection ----
  fold_qkv<<<dim3(HEADS, BATCH, 4), blk, 0, stream>>>(Tt1, Tt2, S1, S2, Wq, bq, Wkv, bkv, qr, kr, vr);
  region_attn<<<dim3(HEADS, BATCH), blk, 0, stream>>>(qr, kr, vr, Wout, Mf);
  cvt_f2b<<<dim3(BATCH * 256 * 512 / 256), blk, 0, stream>>>(Mf, M_b, BATCH * 256 * 512);
  mfma_final<<<dim3(N / 128, 2, BATCH), blk, 0, stream>>>(M_b, bout, buf1, tgt, alpha, out, N);
}

// Round 2
// 672.369 us; speedup vs baseline: 1.1203x; 1.0984x over previous
//
#include <hip/hip_runtime.h>
#include <math.h>

#define NPIX 9216   // 96*96
#define BATCH 8
#define HEADS 8
#define KSLICES 8

typedef __bf16 bf16;
typedef __bf16 bf16x8 __attribute__((ext_vector_type(8)));
typedef __bf16 bf16x4 __attribute__((ext_vector_type(4)));
typedef __bf16 bf16x2 __attribute__((ext_vector_type(2)));
typedef float f32x4 __attribute__((ext_vector_type(4)));

__device__ __forceinline__ void load_lds16(const bf16* g, bf16* l) {
  __builtin_amdgcn_global_load_lds(
      (const __attribute__((address_space(1))) void*)g,
      (__attribute__((address_space(3))) void*)l, 16, 0, 0);
}

// ---------- fp32 -> bf16 elementwise ----------
__global__ __launch_bounds__(256) void cvt_f2b(const float* __restrict__ in,
                                               bf16* __restrict__ out, int n) {
  int i = blockIdx.x * 256 + threadIdx.x;
  if (i < n) out[i] = (bf16)in[i];
}

// ---------- transpose+cvt: (B,C,N) fp32 -> (B,N,C) bf16  AND (B,C,N) bf16 ----------
__global__ __launch_bounds__(256) void transpose_cvt(
    const float* __restrict__ in, bf16* __restrict__ out,
    bf16* __restrict__ outN, int C, int N) {
  __shared__ float tile[32][33];
  int b = blockIdx.z;
  int n0 = blockIdx.x * 32, c0 = blockIdx.y * 32;
  int tx = threadIdx.x & 31, ty = threadIdx.x >> 5;
#pragma unroll
  for (int k = 0; k < 4; ++k) {
    float v = in[((size_t)b * C + c0 + ty + k * 8) * N + n0 + tx];
    tile[ty + k * 8][tx] = v;
    outN[((size_t)b * C + c0 + ty + k * 8) * N + n0 + tx] = (bf16)v;
  }
  __syncthreads();
#pragma unroll
  for (int k = 0; k < 4; ++k)
    out[((size_t)b * N + n0 + ty + k * 8) * C + c0 + tx] = (bf16)tile[tx][ty + k * 8];
}

// ---------- fused channel-softmax (512 ch) + rowsum + optional transpose ----------
__global__ __launch_bounds__(256) void softmax_fused(
    bf16* __restrict__ A, float* __restrict__ S, bf16* __restrict__ At,
    int N, int writeT) {
  __shared__ bf16 tile[512][34];
  __shared__ float redm[8][32];
  __shared__ float reds[8][32];
  int b = blockIdx.y;
  int n0 = blockIdx.x * 32;
  bf16* Ab = A + (size_t)b * 512 * N;
  int t = threadIdx.x;
#pragma unroll 8
  for (int i = 0; i < 32; ++i) {
    int idx = i * 256 + t;
    int c = idx >> 4, ch = idx & 15;
    *(bf16x2*)&tile[c][ch * 2] = *(const bf16x2*)&Ab[(size_t)c * N + n0 + ch * 2];
  }
  __syncthreads();
  int n = t & 31, oct = t >> 5;
  float m = -1e30f;
#pragma unroll 8
  for (int k = 0; k < 64; ++k) m = fmaxf(m, (float)tile[k * 8 + oct][n]);
  redm[oct][n] = m;
  __syncthreads();
  if (t < 32) {
    float mm = redm[0][t];
#pragma unroll
    for (int o = 1; o < 8; ++o) mm = fmaxf(mm, redm[o][t]);
    redm[0][t] = mm;
  }
  __syncthreads();
  float mm = redm[0][n];
  float s = 0.f;
#pragma unroll 8
  for (int k = 0; k < 64; ++k) {
    int c = k * 8 + oct;
    float e = expf((float)tile[c][n] - mm);
    s += e;
    tile[c][n] = (bf16)e;
  }
  reds[oct][n] = s;
  __syncthreads();
  if (t < 32) {
    float ss = reds[0][t];
#pragma unroll
    for (int o = 1; o < 8; ++o) ss += reds[o][t];
    reds[0][t] = ss;
  }
  __syncthreads();
  float inv = 1.f / reds[0][n];
#pragma unroll 8
  for (int k = 0; k < 64; ++k) {
    int c = k * 8 + oct;
    tile[c][n] = (bf16)((float)tile[c][n] * inv);
  }
  __syncthreads();
#pragma unroll 8
  for (int i = 0; i < 32; ++i) {
    int idx = i * 256 + t;
    int c = idx >> 4, ch = idx & 15;
    *(bf16x2*)&Ab[(size_t)c * N + n0 + ch * 2] = *(const bf16x2*)&tile[c][ch * 2];
  }
  {
    int c0 = 2 * t, c1 = 2 * t + 1;
    float s0 = 0.f, s1 = 0.f;
#pragma unroll 8
    for (int nn = 0; nn < 32; ++nn) {
      s0 += (float)tile[c0][nn];
      s1 += (float)tile[c1][nn];
    }
    atomicAdd(&S[(size_t)b * 512 + c0], s0);
    atomicAdd(&S[(size_t)b * 512 + c1], s1);
  }
  if (writeT) {
    bf16* Atb = At + (size_t)b * N * 512;
#pragma unroll 4
    for (int nn = 0; nn < 32; ++nn) {
      bf16x2 v = {tile[2 * t][nn], tile[2 * t + 1][nn]};
      *(bf16x2*)&Atb[(size_t)(n0 + nn) * 512 + 2 * t] = v;
    }
  }
}

// ---------- MFMA conv: Y[b,o,n](bf16) = bias[o] + sum_c W[o,c]*Xt[b,n,c] ----------
__global__ __launch_bounds__(256) void mfma_conv(
    const bf16* __restrict__ W, const float* __restrict__ bias,
    const bf16* __restrict__ Xt, bf16* __restrict__ Y, int O, int N) {
  const int K = 256;
  __shared__ bf16 As[128 * 32];
  __shared__ bf16 Bs[128 * 32];
  int b = blockIdx.z;
  int n0 = blockIdx.x * 128, o0 = blockIdx.y * 128;
  const bf16* Xb = Xt + (size_t)b * N * K;
  int t = threadIdx.x;
  int lane = t & 63, wave = t >> 6;
  int wr = wave >> 1, wc = wave & 1;
  f32x4 acc[4][4] = {};
  for (int k0 = 0; k0 < K; k0 += 32) {
#pragma unroll
    for (int p = 0; p < 2; ++p) {
      int u = p * 256 + t;
      int ub = p * 256 + (t & 192);
      load_lds16(&W[(size_t)(o0 + (u >> 2)) * K + k0 + (u & 3) * 8], &As[ub * 8]);
      load_lds16(&Xb[(size_t)(n0 + (u >> 2)) * K + k0 + (u & 3) * 8], &Bs[ub * 8]);
    }
    __syncthreads();
    bf16x8 bfrag[4];
#pragma unroll
    for (int j = 0; j < 4; ++j)
      bfrag[j] = *(const bf16x8*)&Bs[(wc * 64 + j * 16 + (lane & 15)) * 32 + (lane >> 4) * 8];
#pragma unroll
    for (int i = 0; i < 4; ++i) {
      bf16x8 a = *(const bf16x8*)&As[(wr * 64 + i * 16 + (lane & 15)) * 32 + (lane >> 4) * 8];
#pragma unroll
      for (int j = 0; j < 4; ++j)
        acc[i][j] = __builtin_amdgcn_mfma_f32_16x16x32_bf16(a, bfrag[j], acc[i][j], 0, 0, 0);
    }
    __syncthreads();
  }
  bf16* Yb = Y + (size_t)b * O * N;
  int quad = lane >> 4, col16 = lane & 15;
#pragma unroll
  for (int i = 0; i < 4; ++i) {
#pragma unroll
    for (int reg = 0; reg < 4; ++reg) {
      int row = o0 + wr * 64 + i * 16 + quad * 4 + reg;
      float bv = bias[row];
#pragma unroll
      for (int j = 0; j < 4; ++j) {
        int col = n0 + wc * 64 + j * 16 + col16;
        Yb[(size_t)row * N + col] = (bf16)(acc[i][j][reg] + bv);
      }
    }
  }
}

// ---------- gemm_T (MFMA, split-K, non-atomic partials) ----------
// Tp[b][ks][r][c] = sum_{n in slice ks} Rm[b,r,n]*Xb[b,c,n]
__global__ __launch_bounds__(256) void gemm_T_mfma(
    const bf16* __restrict__ Rm, const bf16* __restrict__ Xb_,
    float* __restrict__ Tp, int N) {
  __shared__ bf16 As[128 * 32];
  __shared__ bf16 Bs[128 * 32];
  int z = blockIdx.z;
  int b = z >> 3, ks = z & 7;
  int klen = N / KSLICES;
  int kbase = ks * klen;
  int c0 = blockIdx.x * 128, r0 = blockIdx.y * 128;
  const bf16* Rb = Rm + (size_t)b * 512 * N;
  const bf16* Xc = Xb_ + (size_t)b * 256 * N;
  int t = threadIdx.x;
  int lane = t & 63, wave = t >> 6;
  int wr = wave >> 1, wc = wave & 1;
  f32x4 acc[4][4] = {};
  for (int kk = kbase; kk < kbase + klen; kk += 32) {
#pragma unroll
    for (int p = 0; p < 2; ++p) {
      int u = p * 256 + t;
      int ub = p * 256 + (t & 192);
      load_lds16(&Rb[(size_t)(r0 + (u >> 2)) * N + kk + (u & 3) * 8], &As[ub * 8]);
      load_lds16(&Xc[(size_t)(c0 + (u >> 2)) * N + kk + (u & 3) * 8], &Bs[ub * 8]);
    }
    __syncthreads();
    bf16x8 bfrag[4];
#pragma unroll
    for (int j = 0; j < 4; ++j)
      bfrag[j] = *(const bf16x8*)&Bs[(wc * 64 + j * 16 + (lane & 15)) * 32 + (lane >> 4) * 8];
#pragma unroll
    for (int i = 0; i < 4; ++i) {
      bf16x8 a = *(const bf16x8*)&As[(wr * 64 + i * 16 + (lane & 15)) * 32 + (lane >> 4) * 8];
#pragma unroll
      for (int j = 0; j < 4; ++j)
        acc[i][j] = __builtin_amdgcn_mfma_f32_16x16x32_bf16(a, bfrag[j], acc[i][j], 0, 0, 0);
    }
    __syncthreads();
  }
  int quad = lane >> 4, col16 = lane & 15;
  float* Tb = Tp + ((size_t)b * KSLICES + ks) * 512 * 256;
#pragma unroll
  for (int i = 0; i < 4; ++i) {
#pragma unroll
    for (int reg = 0; reg < 4; ++reg) {
      int r = r0 + wr * 64 + i * 16 + quad * 4 + reg;
#pragma unroll
      for (int j = 0; j < 4; ++j) {
        int c = c0 + wc * 64 + j * 16 + col16;
        Tb[(size_t)r * 256 + c] = acc[i][j][reg];
      }
    }
  }
}

// ---------- reduce split-K partials: Tt[b][r][c] = sum_ks Tp[b][ks][r][c] ----------
__global__ __launch_bounds__(256) void reduce_T(const float* __restrict__ Tp,
                                                float* __restrict__ Tt) {
  // one float4 per thread over BATCH*512*256 elems
  int f = blockIdx.x * 256 + threadIdx.x;          // float4 index, 0..262143
  int b = f >> 15;                                  // / 32768
  int inner = f & 32767;
  const f32x4* P = (const f32x4*)Tp;
  f32x4 s = P[((size_t)b * KSLICES) * 32768 + inner];
#pragma unroll
  for (int ks = 1; ks < KSLICES; ++ks)
    s += P[((size_t)b * KSLICES + ks) * 32768 + inner];
  ((f32x4*)Tt)[(size_t)b * 32768 + inner] = s;
}

// ---------- fold projections into region space (fp32, LDS-staged, c-split) ----------
// grid (HEADS, BATCH, 4). qr/kr/vr pre-zeroed; atomicAdd accumulate.
__global__ __launch_bounds__(256) void fold_qkv(
    const float* __restrict__ Tt1, const float* __restrict__ Tt2,
    const float* __restrict__ S1, const float* __restrict__ S2,
    const float* __restrict__ Wq, const float* __restrict__ bq,
    const float* __restrict__ Wkv, const float* __restrict__ bkv,
    float* __restrict__ qr, float* __restrict__ kr, float* __restrict__ vr) {
  __shared__ float T1s[64][65];
  __shared__ float T2s[64][65];
  __shared__ float Wqs[32][65];
  __shared__ float Wks[64][65];
  int h = blockIdx.x, b = blockIdx.y;
  int c0 = blockIdx.z * 64;
  int t = threadIdx.x;
  for (int i = t; i < 64 * 64; i += 256) {
    int row = i >> 6, col = i & 63;
    T1s[row][col] = Tt1[((size_t)b * 512 + h * 64 + row) * 256 + c0 + col];
    T2s[row][col] = Tt2[((size_t)b * 512 + h * 64 + row) * 256 + c0 + col];
    Wks[row][col] = Wkv[(size_t)(h * 64 + row) * 256 + c0 + col];
  }
  for (int i = t; i < 32 * 64; i += 256) {
    int row = i >> 6, col = i & 63;
    Wqs[row][col] = Wq[(size_t)(h * 32 + row) * 256 + c0 + col];
  }
  __syncthreads();
  int r = t & 63, d0 = (t >> 6) * 8;
  float aq[8] = {}, ak[8] = {}, av[8] = {};
#pragma unroll 8
  for (int c = 0; c < 64; ++c) {
    float t1 = T1s[r][c];
    float t2 = T2s[r][c];
#pragma unroll
    for (int i = 0; i < 8; ++i) {
      int d = d0 + i;
      aq[i] += Wqs[d][c] * t1;
      ak[i] += Wks[d][c] * t2;
      av[i] += Wks[32 + d][c] * t2;
    }
  }
  if (blockIdx.z == 0) {
    float s1 = S1[(size_t)b * 512 + h * 64 + r];
    float s2 = S2[(size_t)b * 512 + h * 64 + r];
#pragma unroll
    for (int i = 0; i < 8; ++i) {
      int d = d0 + i;
      aq[i] += bq[h * 32 + d] * s1;
      ak[i] += bkv[h * 64 + d] * s2;
      av[i] += bkv[h * 64 + 32 + d] * s2;
    }
  }
  size_t off = ((size_t)b * HEADS + h) * 32 * 64;
#pragma unroll
  for (int i = 0; i < 8; ++i) {
    int d = d0 + i;
    atomicAdd(&qr[off + (size_t)d * 64 + r], aq[i]);
    atomicAdd(&kr[off + (size_t)d * 64 + r], ak[i]);
    atomicAdd(&vr[off + (size_t)d * 64 + r], av[i]);
  }
}

// ---------- region attention + Wout fold (fp32). One block per (b,h). ----------
__global__ __launch_bounds__(256) void region_attn(
    const float* __restrict__ qr, const float* __restrict__ kr,
    const float* __restrict__ vr, const float* __restrict__ Wout,
    float* __restrict__ M) {
  int h = blockIdx.x, b = blockIdx.y;
  __shared__ float qrs[32 * 64];
  __shared__ float krs[32 * 64];
  __shared__ float vrs[32 * 64];
  __shared__ float sc[64][65];
  __shared__ float vals[32][64];
  size_t off = ((size_t)b * HEADS + h) * 32 * 64;
  int t = threadIdx.x;
  for (int i = t; i < 2048; i += 256) {
    qrs[i] = qr[off + i];
    krs[i] = kr[off + i];
    vrs[i] = vr[off + i];
  }
  __syncthreads();
  for (int idx = t; idx < 4096; idx += 256) {
    int qq = idx >> 6, kk = idx & 63;
    float s = 0.f;
#pragma unroll
    for (int d = 0; d < 32; ++d) s += qrs[d * 64 + qq] * krs[d * 64 + kk];
    sc[qq][kk] = s * 0.17677669529663687f;
  }
  __syncthreads();
  if (t < 64) {
    float m = -1e30f;
    for (int k = 0; k < 64; ++k) m = fmaxf(m, sc[t][k]);
    float s = 0.f;
    for (int k = 0; k < 64; ++k) { float e = expf(sc[t][k] - m); sc[t][k] = e; s += e; }
    float inv = 1.f / s;
    for (int k = 0; k < 64; ++k) sc[t][k] *= inv;
  }
  __syncthreads();
  for (int idx = t; idx < 2048; idx += 256) {
    int d = idx >> 6, qq = idx & 63;
    float s = 0.f;
#pragma unroll
    for (int k = 0; k < 64; ++k) s += vrs[d * 64 + k] * sc[qq][k];
    vals[d][qq] = s;
  }
  __syncthreads();
  int o = t;
  float w[32];
#pragma unroll
  for (int d = 0; d < 32; ++d) w[d] = Wout[(size_t)o * 256 + h * 32 + d];
  float* Mp = M + ((size_t)b * 256 + o) * 512 + h * 64;
  for (int r = 0; r < 64; ++r) {
    float s = 0.f;
#pragma unroll
    for (int d = 0; d < 32; ++d) s += w[d] * vals[d][r];
    Mp[r] = s;
  }
}

// ---------- final MFMA: out[b,o,n] = tgt + alpha*(bout[o] + sum_j M[b,o,j]*Rqt[b,n,j]) ----------
__global__ __launch_bounds__(256) void mfma_final(
    const bf16* __restrict__ Mb_, const float* __restrict__ bout,
    const bf16* __restrict__ Rqt, const float* __restrict__ tgt,
    const float* __restrict__ alpha_p, float* __restrict__ Y, int N) {
  const int K = 512;
  __shared__ bf16 As[128 * 32];
  __shared__ bf16 Bs[128 * 32];
  int b = blockIdx.z;
  int n0 = blockIdx.x * 128, o0 = blockIdx.y * 128;
  const bf16* Ab = Mb_ + (size_t)b * 256 * K;
  const bf16* Bb = Rqt + (size_t)b * N * K;
  int t = threadIdx.x;
  int lane = t & 63, wave = t >> 6;
  int wr = wave >> 1, wc = wave & 1;
  f32x4 acc[4][4] = {};
  for (int k0 = 0; k0 < K; k0 += 32) {
#pragma unroll
    for (int p = 0; p < 2; ++p) {
      int u = p * 256 + t;
      int ub = p * 256 + (t & 192);
      load_lds16(&Ab[(size_t)(o0 + (u >> 2)) * K + k0 + (u & 3) * 8], &As[ub * 8]);
      load_lds16(&Bb[(size_t)(n0 + (u >> 2)) * K + k0 + (u & 3) * 8], &Bs[ub * 8]);
    }
    __syncthreads();
    bf16x8 bfrag[4];
#pragma unroll
    for (int j = 0; j < 4; ++j)
      bfrag[j] = *(const bf16x8*)&Bs[(wc * 64 + j * 16 + (lane & 15)) * 32 + (lane >> 4) * 8];
#pragma unroll
    for (int i = 0; i < 4; ++i) {
      bf16x8 a = *(const bf16x8*)&As[(wr * 64 + i * 16 + (lane & 15)) * 32 + (lane >> 4) * 8];
#pragma unroll
      for (int j = 0; j < 4; ++j)
        acc[i][j] = __builtin_amdgcn_mfma_f32_16x16x32_bf16(a, bfrag[j], acc[i][j], 0, 0, 0);
    }
    __syncthreads();
  }
  float alpha = alpha_p[0];
  const float* Tb = tgt + (size_t)b * 256 * N;
  float* Yb = Y + (size_t)b * 256 * N;
  int quad = lane >> 4, col16 = lane & 15;
#pragma unroll
  for (int i = 0; i < 4; ++i) {
#pragma unroll
    for (int reg = 0; reg < 4; ++reg) {
      int row = o0 + wr * 64 + i * 16 + quad * 4 + reg;
      float bv = bout[row];
#pragma unroll
      for (int j = 0; j < 4; ++j) {
        int col = n0 + wc * 64 + j * 16 + col16;
        size_t idx = (size_t)row * N + col;
        Yb[idx] = Tb[idx] + alpha * (acc[i][j][reg] + bv);
      }
    }
  }
}

extern "C" void kernel_launch(void* const* d_in, const int* in_sizes, int n_in,
                              void* d_out, int out_size, void* d_ws, size_t ws_size,
                              hipStream_t stream) {
  const float* src  = (const float*)d_in[0];
  const float* tgt  = (const float*)d_in[1];
  const float* Wq   = (const float*)d_in[2];
  const float* bq   = (const float*)d_in[3];
  const float* Wkv  = (const float*)d_in[4];
  const float* bkv  = (const float*)d_in[5];
  const float* Wrq  = (const float*)d_in[6];
  const float* brq  = (const float*)d_in[7];
  const float* Wrk  = (const float*)d_in[8];
  const float* brk  = (const float*)d_in[9];
  const float* Wout = (const float*)d_in[10];
  const float* bout = (const float*)d_in[11];
  const float* alpha = (const float*)d_in[12];
  float* out = (float*)d_out;

  const int N = NPIX;
  char* p = (char*)d_ws;
  bf16* xt    = (bf16*)p;  p += (size_t)BATCH * N * 256 * 2;        // 37.7 MB
  bf16* buf1  = (bf16*)p;  p += (size_t)BATCH * 512 * N * 2;        // 75.5 MB
  bf16* buf2  = (bf16*)p;  p += (size_t)BATCH * 512 * N * 2;        // 75.5 MB
  float* Tt1  = (float*)p; p += (size_t)BATCH * 512 * 256 * 4;      // 4 MB
  float* Tt2  = (float*)p; p += (size_t)BATCH * 512 * 256 * 4;      // 4 MB
  float* S1   = (float*)p; p += (size_t)BATCH * 512 * 4;
  float* S2   = (float*)p; p += (size_t)BATCH * 512 * 4;
  float* qr   = (float*)p; p += (size_t)BATCH * HEADS * 32 * 64 * 4;
  float* kr   = (float*)p; p += (size_t)BATCH * HEADS * 32 * 64 * 4;
  float* vr   = (float*)p; p += (size_t)BATCH * HEADS * 32 * 64 * 4;
  float* Mf   = (float*)p; p += (size_t)BATCH * 256 * 512 * 4;      // 4 MB
  bf16* Wrk_b = (bf16*)p;  p += (size_t)512 * 256 * 2;
  bf16* Wrq_b = (bf16*)p;  p += (size_t)512 * 256 * 2;
  bf16* M_b   = (bf16*)p;  p += (size_t)BATCH * 256 * 512 * 2;
  bf16* xb    = (bf16*)p;  p += (size_t)BATCH * 256 * N * 2;        // 37.7 MB (shared by both phases)
  float* Tp   = (float*)p; p += (size_t)BATCH * KSLICES * 512 * 256 * 4;  // 33.5 MB (shared)

  dim3 blk(256);
  // zero accumulators: S1,S2,qr,kr,vr are contiguous in ws
  hipMemsetAsync(S1, 0,
                 ((size_t)2 * BATCH * 512 + (size_t)3 * BATCH * HEADS * 32 * 64) * 4,
                 stream);
  // weights -> bf16
  cvt_f2b<<<dim3(512 * 256 / 256), blk, 0, stream>>>(Wrk, Wrk_b, 512 * 256);
  cvt_f2b<<<dim3(512 * 256 / 256), blk, 0, stream>>>(Wrq, Wrq_b, 512 * 256);

  // ---- Rk phase ----
  transpose_cvt<<<dim3(N / 32, 8, BATCH), blk, 0, stream>>>(src, xt, xb, 256, N);
  mfma_conv<<<dim3(N / 128, 4, BATCH), blk, 0, stream>>>(Wrk_b, brk, xt, buf1, 512, N);
  softmax_fused<<<dim3(N / 32, BATCH), blk, 0, stream>>>(buf1, S2, (bf16*)nullptr, N, 0);
  gemm_T_mfma<<<dim3(2, 4, BATCH * KSLICES), blk, 0, stream>>>(buf1, xb, Tp, N);
  reduce_T<<<dim3(BATCH * 512 * 256 / 4 / 256), blk, 0, stream>>>(Tp, Tt2);

  // ---- Rq phase ----
  transpose_cvt<<<dim3(N / 32, 8, BATCH), blk, 0, stream>>>(tgt, xt, xb, 256, N);
  mfma_conv<<<dim3(N / 128, 4, BATCH), blk, 0, stream>>>(Wrq_b, brq, xt, buf2, 512, N);
  softmax_fused<<<dim3(N / 32, BATCH), blk, 0, stream>>>(buf2, S1, buf1, N, 1);
  gemm_T_mfma<<<dim3(2, 4, BATCH * KSLICES), blk, 0, stream>>>(buf2, xb, Tp, N);
  reduce_T<<<dim3(BATCH * 512 * 256 / 4 / 256), blk, 0, stream>>>(Tp, Tt1);

  // ---- fold, attention, back-projection ----
  fold_qkv<<<dim3(HEADS, BATCH, 4), blk, 0, stream>>>(Tt1, Tt2, S1, S2, Wq, bq, Wkv, bkv, qr, kr, vr);
  region_attn<<<dim3(HEADS, BATCH), blk, 0, stream>>>(qr, kr, vr, Wout, Mf);
  cvt_f2b<<<dim3(BATCH * 256 * 512 / 256), blk, 0, stream>>>(Mf, M_b, BATCH * 256 * 512);
  mfma_final<<<dim3(N / 128, 2, BATCH), blk, 0, stream>>>(M_b, bout, buf1, tgt, alpha, out, N);
}